// Round 4
// baseline (262.049 us; speedup 1.0000x reference)
//
#include <hip/hip_runtime.h>

#define DIM 4096
#define F4  1024           // float4 per row
#define BLK 256
#define RPB 8              // rows per block
#define NB3 (3 * DIM / RPB)   // 1536 blocks for the 3-matrix matvec
#define NBO (DIM / RPB)       // 512 blocks for the output matvec

__device__ __forceinline__ float dot4(float4 a, float4 b) {
  return a.x * b.x + a.y * b.y + a.z * b.z + a.w * b.w;
}

__device__ __forceinline__ float wave_reduce(float s) {
#pragma unroll
  for (int off = 32; off > 0; off >>= 1) s += __shfl_down(s, off);
  return s;
}

__device__ __forceinline__ float4 mix4(float4 xi, float4 si, float4 m) {
  float4 r;
  r.x = fmaf(xi.x - si.x, m.x, si.x);
  r.y = fmaf(xi.y - si.y, m.y, si.y);
  r.z = fmaf(xi.z - si.z, m.z, si.z);
  r.w = fmaf(xi.w - si.w, m.w, si.w);
  return r;
}

// ---------- kernel 1: mix + 3-matrix matvec, one row per (wave,iter) ----------
__global__ void __launch_bounds__(BLK) matvec3_rows(
    const float* __restrict__ x, const float* __restrict__ sxx,
    const float* __restrict__ tmk, const float* __restrict__ tmv,
    const float* __restrict__ tmr,
    const float* __restrict__ wr, const float* __restrict__ wk,
    const float* __restrict__ wv,
    float* __restrict__ o_rr, float* __restrict__ o_k, float* __restrict__ o_v) {
  __shared__ float4 xs[F4];   // 16 KB mixed-x for this block's matrix
  const int t = threadIdx.x;
  // XCD-contiguous swizzle: XCD k streams a dense 1/8 of the weight space
  const int b = (blockIdx.x & 7) * (NB3 / 8) + (blockIdx.x >> 3);
  const int m = b / (DIM / RPB);     // 0: rec, 1: key, 2: val
  const int rg = b % (DIM / RPB);    // row group (8 rows)

  const float* mixv = (m == 0) ? tmr : (m == 1) ? tmk : tmv;
  const float4* w4 = (const float4*)((m == 0) ? wr : (m == 1) ? wk : wv);
  float* out = (m == 0) ? o_rr : (m == 1) ? o_k : o_v;

  const float4* x4 = (const float4*)x;
  const float4* s4 = (const float4*)sxx;
  const float4* m4 = (const float4*)mixv;
#pragma unroll
  for (int p = 0; p < 4; ++p) {
    int i = t + p * BLK;
    xs[i] = mix4(x4[i], s4[i], m4[i]);
  }
  __syncthreads();

  const int wave = t >> 6, lane = t & 63;
  // x resident in 64 VGPRs per lane
  float4 xf[16];
#pragma unroll
  for (int j = 0; j < 16; ++j) xf[j] = xs[j * 64 + lane];

#pragma unroll
  for (int rr2 = 0; rr2 < 2; ++rr2) {
    const int row = rg * RPB + wave * 2 + rr2;
    const float4* wp = w4 + (size_t)row * F4 + lane;
    float acc = 0.f;
    float4 wbuf[8];
#pragma unroll
    for (int j = 0; j < 8; ++j) wbuf[j] = wp[j * 64];
#pragma unroll
    for (int j = 0; j < 8; ++j) acc += dot4(wbuf[j], xf[j]);
#pragma unroll
    for (int j = 0; j < 8; ++j) wbuf[j] = wp[(8 + j) * 64];
#pragma unroll
    for (int j = 0; j < 8; ++j) acc += dot4(wbuf[j], xf[8 + j]);
    acc = wave_reduce(acc);
    if (lane == 0) out[row] = acc;
  }
}

// ---------- kernel 2: elementwise WKV + state update ----------
__global__ void __launch_bounds__(BLK) wkv_kernel(
    const float* __restrict__ x, const float* __restrict__ aa,
    const float* __restrict__ bb, const float* __restrict__ pp,
    const float* __restrict__ t_decay, const float* __restrict__ t_first,
    const float* __restrict__ k, const float* __restrict__ v,
    const float* __restrict__ rr,
    float* __restrict__ rab, float* __restrict__ out_x,
    float* __restrict__ out_aa, float* __restrict__ out_bb,
    float* __restrict__ out_pp) {
  int i = blockIdx.x * BLK + threadIdx.x;
  float kk = k[i], vv = v[i];
  float r = 1.0f / (1.0f + expf(-rr[i]));
  float ppi = pp[i], aai = aa[i], bbi = bb[i];
  float ww = t_first[i] + kk;
  float p = fmaxf(ppi, ww);
  float e1 = expf(ppi - p), e2 = expf(ww - p);
  float a = e1 * aai + e2 * vv;
  float b = e1 * bbi + e2;
  rab[i] = r * (a / b);
  float ww2 = ppi + t_decay[i];
  float p2 = fmaxf(ww2, kk);
  float e1b = expf(ww2 - p2), e2b = expf(kk - p2);
  out_x[i] = x[i];
  out_aa[i] = e1b * aai + e2b * vv;
  out_bb[i] = e1b * bbi + e2b;
  out_pp[i] = p2;
}

// ---------- kernel 3: y = w_out @ rab, same row-per-wave structure ----------
__global__ void __launch_bounds__(BLK) matvec_out_rows(
    const float* __restrict__ w, const float* __restrict__ xin,
    float* __restrict__ y) {
  __shared__ float4 xs[F4];
  const int t = threadIdx.x;
  const int b = (blockIdx.x & 7) * (NBO / 8) + (blockIdx.x >> 3);
  const int rg = b;

  const float4* x4 = (const float4*)xin;
#pragma unroll
  for (int p = 0; p < 4; ++p) {
    int i = t + p * BLK;
    xs[i] = x4[i];
  }
  __syncthreads();

  const int wave = t >> 6, lane = t & 63;
  float4 xf[16];
#pragma unroll
  for (int j = 0; j < 16; ++j) xf[j] = xs[j * 64 + lane];

  const float4* w4 = (const float4*)w;
#pragma unroll
  for (int rr2 = 0; rr2 < 2; ++rr2) {
    const int row = rg * RPB + wave * 2 + rr2;
    const float4* wp = w4 + (size_t)row * F4 + lane;
    float acc = 0.f;
    float4 wbuf[8];
#pragma unroll
    for (int j = 0; j < 8; ++j) wbuf[j] = wp[j * 64];
#pragma unroll
    for (int j = 0; j < 8; ++j) acc += dot4(wbuf[j], xf[j]);
#pragma unroll
    for (int j = 0; j < 8; ++j) wbuf[j] = wp[(8 + j) * 64];
#pragma unroll
    for (int j = 0; j < 8; ++j) acc += dot4(wbuf[j], xf[8 + j]);
    acc = wave_reduce(acc);
    if (lane == 0) y[row] = acc;
  }
}

extern "C" void kernel_launch(void* const* d_in, const int* in_sizes, int n_in,
                              void* d_out, int out_size, void* d_ws, size_t ws_size,
                              hipStream_t stream) {
  const float* x       = (const float*)d_in[0];
  const float* sxx     = (const float*)d_in[1];
  const float* aa      = (const float*)d_in[2];
  const float* bb      = (const float*)d_in[3];
  const float* pp      = (const float*)d_in[4];
  const float* w_key   = (const float*)d_in[5];
  const float* w_val   = (const float*)d_in[6];
  const float* w_rec   = (const float*)d_in[7];
  const float* w_out   = (const float*)d_in[8];
  const float* t_decay = (const float*)d_in[9];
  const float* t_first = (const float*)d_in[10];
  const float* t_mix_k = (const float*)d_in[11];
  const float* t_mix_v = (const float*)d_in[12];
  const float* t_mix_r = (const float*)d_in[13];

  float* out    = (float*)d_out;
  float* y      = out;            // output 0
  float* out_x  = out + DIM;      // output 1 (new state_xx = x)
  float* out_aa = out + 2 * DIM;  // output 2
  float* out_bb = out + 3 * DIM;  // output 3
  float* out_pp = out + 4 * DIM;  // output 4

  float* ws  = (float*)d_ws;
  float* k   = ws;
  float* v   = ws + DIM;
  float* rr  = ws + 2 * DIM;
  float* rab = ws + 3 * DIM;

  matvec3_rows<<<NB3, BLK, 0, stream>>>(x, sxx, t_mix_k, t_mix_v, t_mix_r,
                                        w_rec, w_key, w_val, rr, k, v);
  wkv_kernel<<<DIM / BLK, BLK, 0, stream>>>(x, aa, bb, pp, t_decay, t_first,
                                            k, v, rr, rab, out_x, out_aa,
                                            out_bb, out_pp);
  matvec_out_rows<<<NBO, BLK, 0, stream>>>(w_out, rab, y);
}